// Round 1
// baseline (393.638 us; speedup 1.0000x reference)
//
#include <hip/hip_runtime.h>

#define N_TOK 4096
#define DIM   1024
#define NE    8
#define CAP   1280
#define EC    (NE * CAP)          // 10240
#define NEC   (N_TOK * EC)        // 41943040
#define OUT_ELEMS (8 + 2 * NEC)   // 83886088
#define OUT_VEC4  (OUT_ELEMS / 4) // 20971522

// ---------------- Stage 1: logits -> softmax -> top2 ----------------
// One wave per token (4 waves / block). w_g (32 KB) staged in LDS.
__global__ __launch_bounds__(256) void k_logits(const float* __restrict__ x,
                                                const float* __restrict__ wg,
                                                int* __restrict__ top_idx,   // [2*N] k-major
                                                float* __restrict__ top_p) { // [2*N] k-major
    __shared__ float swg[NE * DIM];
    const float4* wg4 = (const float4*)wg;
    float4* swg4 = (float4*)swg;
#pragma unroll
    for (int i = 0; i < 8; ++i) {
        int t = i * 256 + threadIdx.x;
        swg4[t] = wg4[t];
    }
    __syncthreads();

    const int wave = threadIdx.x >> 6;
    const int lane = threadIdx.x & 63;
    const int token = blockIdx.x * 4 + wave;

    const float4* x4 = (const float4*)(x + (size_t)token * DIM);
    float acc[NE];
#pragma unroll
    for (int e = 0; e < NE; ++e) acc[e] = 0.f;

#pragma unroll
    for (int c = 0; c < 4; ++c) {
        float4 xv = x4[c * 64 + lane];
#pragma unroll
        for (int e = 0; e < NE; ++e) {
            float4 wv = swg4[e * 256 + c * 64 + lane];
            acc[e] += xv.x * wv.x + xv.y * wv.y + xv.z * wv.z + xv.w * wv.w;
        }
    }
    // wave (64-lane) butterfly reduce each of the 8 dot products
#pragma unroll
    for (int e = 0; e < NE; ++e) {
        float v = acc[e];
#pragma unroll
        for (int off = 32; off > 0; off >>= 1)
            v += __shfl_xor(v, off, 64);
        acc[e] = v;
    }

    if (lane == 0) {
        float m = acc[0];
#pragma unroll
        for (int e = 1; e < NE; ++e) m = fmaxf(m, acc[e]);
        float pe[NE];
        float s = 0.f;
#pragma unroll
        for (int e = 0; e < NE; ++e) { pe[e] = expf(acc[e] - m); s += pe[e]; }
        float inv = 1.f / s;

        // top-1: first occurrence of max (ties -> lower index, matches lax.top_k)
        int i1 = 0; float v1 = acc[0];
#pragma unroll
        for (int e = 1; e < NE; ++e) if (acc[e] > v1) { v1 = acc[e]; i1 = e; }
        // top-2 over remaining
        int i2 = (i1 == 0) ? 1 : 0; float v2 = acc[i2];
#pragma unroll
        for (int e = 0; e < NE; ++e)
            if (e != i1 && acc[e] > v2) { v2 = acc[e]; i2 = e; }

        top_idx[token]         = i1;
        top_idx[N_TOK + token] = i2;
        top_p[token]           = pe[i1] * inv;
        top_p[N_TOK + token]   = pe[i2] * inv;
    }
}

// ---------------- Stage 2: sequential-order ranking (one wave) ----------------
// j = k*N + n ordering; rank_j = #{i<j : e_i == e_j}; keep iff rank < CAP.
__global__ __launch_bounds__(64) void k_rank(const int* __restrict__ top_idx,
                                             int* __restrict__ dest,     // [2*N]
                                             float* __restrict__ used) { // [8]
    __shared__ int se[2 * N_TOK]; // 32 KB: all 8192 expert ids
    const int lane = threadIdx.x;
    const int4* ti4 = (const int4*)top_idx;
    int4* se4 = (int4*)se;
#pragma unroll
    for (int i = 0; i < 32; ++i)
        se4[i * 64 + lane] = ti4[i * 64 + lane];
    __syncthreads();

    // pass 1: local histogram over this lane's 128 contiguous assignments
    int cnt[NE];
#pragma unroll
    for (int e = 0; e < NE; ++e) cnt[e] = 0;
    const int base = lane * 128;
    for (int jj = 0; jj < 128; ++jj) cnt[se[base + jj]]++;

    // exclusive scan across lanes, per expert
    int excl[NE], tot[NE];
#pragma unroll
    for (int e = 0; e < NE; ++e) {
        int v = cnt[e];
        int inc = v;
#pragma unroll
        for (int off = 1; off < 64; off <<= 1) {
            int u = __shfl_up(inc, off, 64);
            if (lane >= off) inc += u;
        }
        excl[e] = inc - v;
        tot[e] = __shfl(inc, 63, 64);
    }
    if (lane < NE) used[lane] = (float)min(tot[lane], CAP);

    // pass 2: assign ranks, emit scatter destinations
    int run[NE];
#pragma unroll
    for (int e = 0; e < NE; ++e) run[e] = excl[e];
    for (int jj = 0; jj < 128; ++jj) {
        int j = base + jj;
        int e = se[j];
        int r = run[e]++;
        int n = j & (N_TOK - 1);
        dest[j] = (r < CAP) ? (n * EC + e * CAP + r) : -1;
    }
}

// ---------------- Stage 3: zero-fill the whole output ----------------
__global__ __launch_bounds__(256) void k_fill(float4* __restrict__ out, int n4) {
    int i = blockIdx.x * blockDim.x + threadIdx.x;
    const int stride = gridDim.x * blockDim.x;
    const float4 z = {0.f, 0.f, 0.f, 0.f};
    for (; i < n4; i += stride) out[i] = z;
}

// ---------------- Stage 4: scatter weights + mask + used_capacity ----------------
__global__ __launch_bounds__(256) void k_scatter(const int* __restrict__ dest,
                                                 const float* __restrict__ top_p,
                                                 const float* __restrict__ used,
                                                 float* __restrict__ out) {
    int j = blockIdx.x * blockDim.x + threadIdx.x;
    if (j < NE) out[j] = used[j];
    if (j < 2 * N_TOK) {
        int d = dest[j];
        if (d >= 0) {
            out[(size_t)8 + d] = top_p[j];          // cb_weight
            out[(size_t)8 + NEC + d] = 1.0f;        // sec_mask
        }
    }
}

extern "C" void kernel_launch(void* const* d_in, const int* in_sizes, int n_in,
                              void* d_out, int out_size, void* d_ws, size_t ws_size,
                              hipStream_t stream) {
    const float* x  = (const float*)d_in[0];
    const float* wg = (const float*)d_in[1];
    float* out = (float*)d_out;
    char* ws = (char*)d_ws;

    int*   top_idx = (int*)(ws);             // 8192 ints  (32 KB)
    float* top_p   = (float*)(ws + 32768);   // 8192 floats (32 KB)
    int*   dest    = (int*)(ws + 65536);     // 8192 ints  (32 KB)
    float* used    = (float*)(ws + 98304);   // 8 floats

    k_logits<<<N_TOK / 4, 256, 0, stream>>>(x, wg, top_idx, top_p);
    k_rank<<<1, 64, 0, stream>>>(top_idx, dest, used);
    k_fill<<<4096, 256, 0, stream>>>((float4*)out, OUT_VEC4);
    k_scatter<<<(2 * N_TOK + 255) / 256, 256, 0, stream>>>(dest, top_p, used, out);
}

// Round 2
// 391.918 us; speedup vs baseline: 1.0044x; 1.0044x over previous
//
#include <hip/hip_runtime.h>

#define N_TOK 4096
#define DIM   1024
#define NE    8
#define CAP   1280
#define EC    (NE * CAP)          // 10240 floats per token per tensor
#define EC4   (EC / 4)            // 2560 float4 per token row
#define NEC   ((size_t)N_TOK * EC) // 41943040

// ---------------- Stage 1: logits -> softmax -> top2 ----------------
// One wave per token (4 waves / block). w_g (32 KB) staged in LDS.
__global__ __launch_bounds__(256) void k_logits(const float* __restrict__ x,
                                                const float* __restrict__ wg,
                                                int* __restrict__ top_idx,   // [2*N] k-major
                                                float* __restrict__ top_p) { // [2*N] k-major
    __shared__ float swg[NE * DIM];
    const float4* wg4 = (const float4*)wg;
    float4* swg4 = (float4*)swg;
#pragma unroll
    for (int i = 0; i < 8; ++i) {
        int t = i * 256 + threadIdx.x;
        swg4[t] = wg4[t];
    }
    __syncthreads();

    const int wave = threadIdx.x >> 6;
    const int lane = threadIdx.x & 63;
    const int token = blockIdx.x * 4 + wave;

    const float4* x4 = (const float4*)(x + (size_t)token * DIM);
    float acc[NE];
#pragma unroll
    for (int e = 0; e < NE; ++e) acc[e] = 0.f;

#pragma unroll
    for (int c = 0; c < 4; ++c) {
        float4 xv = x4[c * 64 + lane];
#pragma unroll
        for (int e = 0; e < NE; ++e) {
            float4 wv = swg4[e * 256 + c * 64 + lane];
            acc[e] += xv.x * wv.x + xv.y * wv.y + xv.z * wv.z + xv.w * wv.w;
        }
    }
#pragma unroll
    for (int e = 0; e < NE; ++e) {
        float v = acc[e];
#pragma unroll
        for (int off = 32; off > 0; off >>= 1)
            v += __shfl_xor(v, off, 64);
        acc[e] = v;
    }

    if (lane == 0) {
        float m = acc[0];
#pragma unroll
        for (int e = 1; e < NE; ++e) m = fmaxf(m, acc[e]);
        float pe[NE];
        float s = 0.f;
#pragma unroll
        for (int e = 0; e < NE; ++e) { pe[e] = expf(acc[e] - m); s += pe[e]; }
        float inv = 1.f / s;

        int i1 = 0; float v1 = acc[0];
#pragma unroll
        for (int e = 1; e < NE; ++e) if (acc[e] > v1) { v1 = acc[e]; i1 = e; }
        int i2 = (i1 == 0) ? 1 : 0; float v2 = acc[i2];
#pragma unroll
        for (int e = 0; e < NE; ++e)
            if (e != i1 && acc[e] > v2) { v2 = acc[e]; i2 = e; }

        top_idx[token]         = i1;
        top_idx[N_TOK + token] = i2;
        top_p[token]           = pe[i1] * inv;
        top_p[N_TOK + token]   = pe[i2] * inv;
    }
}

// ---------------- Stage 2: rank in j = k*N+n order, build dense slot table ----
__global__ __launch_bounds__(64) void k_rank(const int* __restrict__ top_idx,
                                             const float* __restrict__ top_p,
                                             int* __restrict__ slot_tok,   // [NE*CAP]
                                             float* __restrict__ slot_w,   // [NE*CAP]
                                             float* __restrict__ used) {   // [NE]
    __shared__ int se[2 * N_TOK];
    const int lane = threadIdx.x;
    const int4* ti4 = (const int4*)top_idx;
    int4* se4 = (int4*)se;
#pragma unroll
    for (int i = 0; i < 32; ++i)
        se4[i * 64 + lane] = ti4[i * 64 + lane];
    __syncthreads();

    // pass 1: local histogram over this lane's 128 contiguous assignments
    int cnt[NE];
#pragma unroll
    for (int e = 0; e < NE; ++e) cnt[e] = 0;
    const int base = lane * 128;
    for (int jj = 0; jj < 128; ++jj) cnt[se[base + jj]]++;

    // exclusive scan across lanes, per expert
    int excl[NE], tot[NE];
#pragma unroll
    for (int e = 0; e < NE; ++e) {
        int v = cnt[e];
        int inc = v;
#pragma unroll
        for (int off = 1; off < 64; off <<= 1) {
            int u = __shfl_up(inc, off, 64);
            if (lane >= off) inc += u;
        }
        excl[e] = inc - v;
        tot[e] = __shfl(inc, 63, 64);
    }
    if (lane < NE) used[lane] = (float)min(tot[lane], CAP);

    // pass 2: fill kept slots with (token, weight)
    int run[NE];
#pragma unroll
    for (int e = 0; e < NE; ++e) run[e] = excl[e];
    for (int jj = 0; jj < 128; ++jj) {
        int j = base + jj;
        int e = se[j];
        int r = run[e]++;
        if (r < CAP) {
            slot_tok[e * CAP + r] = j & (N_TOK - 1);
            slot_w[e * CAP + r]   = top_p[j];
        }
    }
    // tail init: slots never filled get token = -1 (disjoint addresses, no hazard)
#pragma unroll
    for (int e = 0; e < NE; ++e) {
        int start = min(tot[e], CAP);
        for (int s = start + lane; s < CAP; s += 64)
            slot_tok[e * CAP + s] = -1;
    }
}

// ---------------- Stage 3: single-pass gather fill of the whole output --------
// Block b handles token b: 2560 float4 of cb_weight + 2560 float4 of sec_mask.
__global__ __launch_bounds__(256) void k_out(const int* __restrict__ slot_tok,
                                             const float* __restrict__ slot_w,
                                             const float* __restrict__ used,
                                             float* __restrict__ out) {
    const int n = blockIdx.x;
    const int t = threadIdx.x;
    if (n == 0 && t < NE) out[t] = used[t];

    float4* cb = (float4*)(out + 8 + (size_t)n * EC);
    float4* mk = (float4*)(out + 8 + NEC + (size_t)n * EC);
    const int4* st4 = (const int4*)slot_tok;
    const float4* sw4 = (const float4*)slot_w;

#pragma unroll
    for (int i = 0; i < EC4 / 256; ++i) {   // 10 iterations
        int v = t + 256 * i;
        int4 tk = st4[v];
        float4 w = sw4[v];
        float4 c, m;
        c.x = (tk.x == n) ? w.x : 0.f;  m.x = (tk.x == n) ? 1.f : 0.f;
        c.y = (tk.y == n) ? w.y : 0.f;  m.y = (tk.y == n) ? 1.f : 0.f;
        c.z = (tk.z == n) ? w.z : 0.f;  m.z = (tk.z == n) ? 1.f : 0.f;
        c.w = (tk.w == n) ? w.w : 0.f;  m.w = (tk.w == n) ? 1.f : 0.f;
        cb[v] = c;
        mk[v] = m;
    }
}

extern "C" void kernel_launch(void* const* d_in, const int* in_sizes, int n_in,
                              void* d_out, int out_size, void* d_ws, size_t ws_size,
                              hipStream_t stream) {
    const float* x  = (const float*)d_in[0];
    const float* wg = (const float*)d_in[1];
    float* out = (float*)d_out;
    char* ws = (char*)d_ws;

    int*   top_idx  = (int*)(ws);                 // 8192 ints   (32 KB)
    float* top_p    = (float*)(ws + 32768);       // 8192 floats (32 KB)
    int*   slot_tok = (int*)(ws + 65536);         // 10240 ints  (40 KB)
    float* slot_w   = (float*)(ws + 106496);      // 10240 floats(40 KB)
    float* used     = (float*)(ws + 147456);      // 8 floats

    k_logits<<<N_TOK / 4, 256, 0, stream>>>(x, wg, top_idx, top_p);
    k_rank<<<1, 64, 0, stream>>>(top_idx, top_p, slot_tok, slot_w, used);
    k_out<<<N_TOK, 256, 0, stream>>>(slot_tok, slot_w, used, out);
}